// Round 13
// baseline (191.395 us; speedup 1.0000x reference)
//
#include <hip/hip_runtime.h>
#include <stdint.h>

#define HH 64
#define WW 64
#define AA 9
#define N_PER (HH*WW*AA)   // 36864
#define NB 4
#define PRE_NMS 6000
#define POST_NMS 300
#define NMS_THRESH 0.7f
#define FEAT_STRIDE 16
#define M 1024             // in-LDS NMS candidate window
#define MW 16              // u64 words per mask row (1024/64)
#define BINS 65536         // 16-bit radix bins (top bits of monotonic key)
#define KSHIFT 48
#define SCAT_MAX 8000      // scatter capacity (Nsel < 6000 + maxbin ~80)

// ws layout (bytes)
#define OFF_TOPB   0u          // 384,000
#define OFF_MSK    393216u     // 524,288
#define OFF_H      917504u     // 1,048,576
#define OFF_SS     1966080u    // 1,048,576
#define OFF_CUR    3014656u    // 1,048,576
#define OFF_B1     4063232u    // 16
#define OFF_NSEL   4063248u    // 16
#define OFF_SCAT   4063264u    // 256,000

__device__ __forceinline__ uint64_t make_key(const float* __restrict__ scores, int b, int j) {
    int a = j >> 12, hw = j & 4095;
    float sc = scores[((size_t)b*18 + 9 + a)*4096 + hw];
    uint32_t u = __float_as_uint(sc);
    u = (u & 0x80000000u) ? ~u : (u | 0x80000000u);   // monotonic float->uint
    uint32_t i = (uint32_t)(hw*9 + a);                // reference flat index
    return ((uint64_t)u << 32) | (uint32_t)(~i);
}

// ---------------- K1: grid-parallel 16-bit histogram ----------------
__global__ void __launch_bounds__(1024) hist_kernel(const float* __restrict__ scores,
                                                    uint32_t* __restrict__ Hg) {
    int tid = blockIdx.x*1024 + threadIdx.x;          // 0..147455
    int b = tid / N_PER;
    int j = tid - b*N_PER;
    uint64_t k64 = make_key(scores, b, j);
    atomicAdd(&Hg[(uint32_t)b*BINS + (uint32_t)(k64 >> KSHIFT)], 1u);
}

// ---------------- K2: per-image suffix scan + cutoff (65536 bins) ----------------
__global__ void __launch_bounds__(1024) scan_cutoff(const uint32_t* __restrict__ Hg,
                                                    uint32_t* __restrict__ SSg,
                                                    uint32_t* __restrict__ CURg,
                                                    uint32_t* __restrict__ B1g,
                                                    uint32_t* __restrict__ NselG) {
    int b = blockIdx.x;
    int t = threadIdx.x;
    __shared__ uint32_t blksum[1024];
    __shared__ int shB1;
    __shared__ uint32_t shNsel;

    uint32_t base = (uint32_t)t * 64u;
    const uint32_t* Hb = Hg + (size_t)b*BINS;
    uint32_t loc[64];
    uint32_t lsum = 0;
    #pragma unroll
    for (int k = 0; k < 16; ++k) {
        uint4 v = ((const uint4*)(Hb + base))[k];
        loc[4*k+0] = v.x; loc[4*k+1] = v.y; loc[4*k+2] = v.z; loc[4*k+3] = v.w;
        lsum += v.x + v.y + v.z + v.w;
    }
    blksum[t] = lsum;
    __syncthreads();
    for (int off = 1; off < 1024; off <<= 1) {        // Hillis-Steele inclusive suffix
        uint32_t add = (t + off < 1024) ? blksum[t + off] : 0u;
        __syncthreads();
        blksum[t] += add;
        __syncthreads();
    }
    uint32_t run = (t < 1023) ? blksum[t + 1] : 0u;
    #pragma unroll
    for (int k = 63; k >= 0; --k) { uint32_t h = loc[k]; loc[k] = run; run += h; }
    #pragma unroll
    for (int k = 0; k < 64; ++k) {
        uint32_t ss   = loc[k];
        uint32_t prev = (k == 0) ? blksum[t] : loc[k-1];
        if (ss < PRE_NMS && prev >= PRE_NMS) { shB1 = (int)(base + (uint32_t)k); shNsel = prev; }
    }
    __syncthreads();
    int B1 = shB1;
    if (t == 0) { B1g[b] = (uint32_t)B1; NselG[b] = shNsel; }
    uint32_t* SSb  = SSg  + (size_t)b*BINS;
    uint32_t* CURb = CURg + (size_t)b*BINS;
    if ((int)base >= B1) {                            // fully above: vector path
        #pragma unroll
        for (int k = 0; k < 16; ++k) {
            uint4 v = make_uint4(loc[4*k+0], loc[4*k+1], loc[4*k+2], loc[4*k+3]);
            ((uint4*)(SSb + base))[k]  = v;
            ((uint4*)(CURb + base))[k] = v;
        }
    } else if ((int)(base + 63u) >= B1) {             // straddling thread: scalar tail
        #pragma unroll
        for (int k = 0; k < 64; ++k) {
            if ((int)(base + (uint32_t)k) >= B1) {
                SSb[base + k]  = loc[k];
                CURb[base + k] = loc[k];
            }
        }
    }
}

// ---------------- K3: grid-parallel scatter (bin-partitioned slots) ----------------
__global__ void __launch_bounds__(1024) scatter_kernel(const float* __restrict__ scores,
                                                       const uint32_t* __restrict__ B1g,
                                                       uint32_t* __restrict__ CURg,
                                                       uint64_t* __restrict__ scatG) {
    int tid = blockIdx.x*1024 + threadIdx.x;
    int b = tid / N_PER;
    int j = tid - b*N_PER;
    uint64_t k64 = make_key(scores, b, j);
    uint32_t bin = (uint32_t)(k64 >> KSHIFT);
    if (bin >= B1g[b]) {
        uint32_t slot = atomicAdd(&CURg[(uint32_t)b*BINS + bin], 1u);
        if (slot < SCAT_MAX) scatG[(uint32_t)b*SCAT_MAX + slot] = k64;
    }
}

// ---------------- K4: grid-parallel rank + decode + direct topb[rank] ----------------
__global__ void __launch_bounds__(1024) rank_decode(const uint64_t* __restrict__ scatG,
                                                    const uint32_t* __restrict__ SSg,
                                                    const uint32_t* __restrict__ CURg,
                                                    const uint32_t* __restrict__ NselG,
                                                    const float* __restrict__ deltas,
                                                    const float* __restrict__ img_info,
                                                    const float* __restrict__ anchors,
                                                    float* __restrict__ topb) {
#pragma clang fp contract(off)
    int b = blockIdx.y;
    uint32_t s = blockIdx.x*1024u + threadIdx.x;
    uint32_t n = min(NselG[b], (uint32_t)SCAT_MAX);
    if (s >= n) return;
    const uint64_t* sg = scatG + (uint32_t)b*SCAT_MAX;
    uint64_t k64 = sg[s];
    uint32_t bin = (uint32_t)(k64 >> KSHIFT);
    uint32_t start = SSg[(uint32_t)b*BINS + bin];
    uint32_t end = min(CURg[(uint32_t)b*BINS + bin], (uint32_t)SCAT_MAX);
    uint32_t cnt = 0;
    uint32_t j = start;
    for (; j + 4 <= end; j += 4) {
        uint64_t a0 = sg[j], a1 = sg[j+1], a2 = sg[j+2], a3 = sg[j+3];
        cnt += (a0 > k64) ? 1u : 0u;
        cnt += (a1 > k64) ? 1u : 0u;
        cnt += (a2 > k64) ? 1u : 0u;
        cnt += (a3 > k64) ? 1u : 0u;
    }
    for (; j < end; ++j) cnt += (sg[j] > k64) ? 1u : 0u;
    uint32_t r = start + cnt;                         // exact global descending rank
    if (r >= PRE_NMS) return;

    uint32_t i = ~(uint32_t)(k64 & 0xFFFFFFFFu);
    int a = (int)(i % 9u);
    int hw = (int)(i / 9u);
    int h = hw >> 6, w = hw & 63;
    float sx = (float)(w * FEAT_STRIDE);
    float sy = (float)(h * FEAT_STRIDE);
    float ax1 = anchors[a*4+0] + sx;
    float ay1 = anchors[a*4+1] + sy;
    float ax2 = anchors[a*4+2] + sx;
    float ay2 = anchors[a*4+3] + sy;
    float width  = ax2 - ax1 + 1.0f;
    float height = ay2 - ay1 + 1.0f;
    float cx = ax1 + 0.5f * width;
    float cy = ay1 + 0.5f * height;
    size_t dbase = ((size_t)b*36 + a*4) * 4096 + hw;
    float dx = deltas[dbase];
    float dy = deltas[dbase + 4096];
    float dw = deltas[dbase + 2*4096];
    float dh = deltas[dbase + 3*4096];
    float pcx = dx * width + cx;
    float pcy = dy * height + cy;
    float pw = (float)exp((double)dw) * width;        // correctly-rounded f32 exp
    float ph = (float)exp((double)dh) * height;
    float x1 = pcx - 0.5f * pw;
    float y1 = pcy - 0.5f * ph;
    float x2 = pcx + 0.5f * pw;
    float y2 = pcy + 0.5f * ph;
    float maxx = img_info[1] - 1.0f;
    float maxy = img_info[0] - 1.0f;
    x1 = fminf(fmaxf(x1, 0.0f), maxx);
    y1 = fminf(fmaxf(y1, 0.0f), maxy);
    x2 = fminf(fmaxf(x2, 0.0f), maxx);
    y2 = fminf(fmaxf(y2, 0.0f), maxy);
    *(float4*)(topb + ((size_t)b*PRE_NMS + r)*4) = make_float4(x1, y1, x2, y2);
}

// =====================================================================
// Kernel 5: suppression bitmask for the TOP-1024 window (unchanged).
// =====================================================================
__global__ void __launch_bounds__(64) nms_mask_small(const float* __restrict__ topb,
                                                     uint64_t* __restrict__ msk) {
#pragma clang fp contract(off)
    int jblock = blockIdx.x;  // 0..15
    int iblock = blockIdx.y;  // 0..15
    int b = blockIdx.z;
    int t = threadIdx.x;      // 0..63
    __shared__ float4 jb[64];
    __shared__ float jarea[64];
    int j0 = jblock*64;
    {
        float4 bj = *(const float4*)(topb + ((size_t)b*PRE_NMS + j0 + t)*4);
        jb[t] = bj;
        jarea[t] = (bj.z - bj.x + 1.0f) * (bj.w - bj.y + 1.0f);
    }
    __syncthreads();
    int i = iblock*64 + t;
    float4 bi = *(const float4*)(topb + ((size_t)b*PRE_NMS + i)*4);
    float areai = (bi.z - bi.x + 1.0f) * (bi.w - bi.y + 1.0f);
    uint64_t bits = 0;
    for (int jj = 0; jj < 64; ++jj) {
        float4 bj = jb[jj];
        float xx1 = fmaxf(bi.x, bj.x);
        float yy1 = fmaxf(bi.y, bj.y);
        float xx2 = fminf(bi.z, bj.z);
        float yy2 = fminf(bi.w, bj.w);
        float iw = fmaxf(0.0f, xx2 - xx1 + 1.0f);
        float ih = fmaxf(0.0f, yy2 - yy1 + 1.0f);
        float inter = iw * ih;
        float iou = inter / ((areai + jarea[jj]) - inter);
        if (iou > NMS_THRESH) bits |= (1ull << jj);
    }
    msk[((size_t)b*M + i)*MW + jblock] = bits;
}

// =====================================================================
// Kernel 6: greedy scan, mask in LDS. 256 threads: 4 waves stage the
// 128 KB mask (4x faster), wave 0 walks with a 1-deep SPECULATIVE row
// prefetch: per keep, compute exact next AND predicted next-next (first
// live excluding next's bit), issue next-next's LDS read one iteration
// early -> ds_read latency hides under the ffs/ballot chain. Mispredict
// (next-next suppressed by next, ~0.3%/iter) re-reads directly.
// =====================================================================
__global__ void __launch_bounds__(256) nms_scan_lds(const uint64_t* __restrict__ msk,
                                                    const float* __restrict__ topb,
                                                    float* __restrict__ out) {
#pragma clang fp contract(off)
    int b = blockIdx.x;
    int tid = threadIdx.x;
    int wid = tid >> 6, lane = tid & 63;
    __shared__ __align__(16) uint64_t rows[M][MW];   // 131,072 B
    __shared__ int keepL[POST_NMS];
    __shared__ float skx1[POST_NMS], sky1[POST_NMS], skx2[POST_NMS], sky2[POST_NMS], skar[POST_NMS];

    // ---- stage 128 KB mask into LDS with all 4 waves ----
    const uint8_t* src0 = (const uint8_t*)(msk + (size_t)b*M*MW);
    uint8_t* dst0 = (uint8_t*)&rows[0][0];
    for (int c = wid; c < (M*MW*8)/1024; c += 4) {   // 32 chunks of 1 KB per wave
        __builtin_amdgcn_global_load_lds(
            (const __attribute__((address_space(1))) uint32_t*)(src0 + c*1024 + lane*16),
            (__attribute__((address_space(3))) uint32_t*)(dst0 + c*1024 + lane*16),
            16, 0, 0);
    }
    asm volatile("s_waitcnt vmcnt(0)" ::: "memory");
    __builtin_amdgcn_sched_barrier(0);
    __syncthreads();

    if (tid < 64) {
        int l = lane;
        uint64_t remv = 0ull;      // lane l<16 owns bits [64l, 64l+64)
        int nkeep = 0;
        int cur = 0;
        bool exhausted = false;

        // prologue: row(0) and speculative row(1)
        uint64_t rvN = (l < MW) ? rows[0][l] : 0ull;
        int pred = 1;
        uint64_t rvP = (l < MW) ? rows[1][l] : 0ull;

        while (true) {
            if (l == 0) keepL[nkeep] = cur;
            nkeep++;
            if (nkeep >= POST_NMS) break;
            remv |= rvN;           // row includes self-bit (IoU=1)
            uint64_t live = (l < MW) ? ~remv : 0ull;
            // exact next keep
            int local = live ? (l*64 + (int)__builtin_ctzll(live)) : 0x7FFFFFFF;
            uint64_t mb = __ballot(live != 0ull);
            if (mb == 0ull) { exhausted = true; break; }
            int next = __builtin_amdgcn_readlane(local, (int)__builtin_ctzll(mb));
            // row for next: speculative hit or direct read
            if (next == pred) {
                rvN = rvP;
            } else {
                rvN = (l < MW) ? rows[next][l] : 0ull;   // rare mispredict
            }
            // predict the following keep: first live after clearing next's bit
            uint64_t live2 = live;
            if (l == (next >> 6)) live2 &= ~(1ull << (next & 63));
            int local2 = live2 ? (l*64 + (int)__builtin_ctzll(live2)) : 0x7FFFFFFF;
            uint64_t mb2 = __ballot(live2 != 0ull);
            int p2 = (mb2 != 0ull) ? __builtin_amdgcn_readlane(local2, (int)__builtin_ctzll(mb2)) : next;
            pred = p2;
            rvP = (l < MW) ? rows[p2][l] : 0ull;         // issued now, used next iter
            cur = next;
        }

        // ---- phase C (exact fallback): ranks 1024..5999, lazy check ----
        if (nkeep < POST_NMS && exhausted) {
            for (int k = l; k < nkeep; k += 64) {
                float4 bx = *(const float4*)(topb + ((size_t)b*PRE_NMS + keepL[k])*4);
                skx1[k] = bx.x; sky1[k] = bx.y; skx2[k] = bx.z; sky2[k] = bx.w;
                skar[k] = (bx.z - bx.x + 1.0f) * (bx.w - bx.y + 1.0f);
            }
            int base = M;
            while (nkeep < POST_NMS && base < PRE_NMS) {
                int c = base + l;
                float4 bc = make_float4(0.f, 0.f, 0.f, 0.f);
                bool sup = true;
                if (c < PRE_NMS) {
                    bc = *(const float4*)(topb + ((size_t)b*PRE_NMS + c)*4);
                    sup = false;
                }
                float ac = (bc.z - bc.x + 1.0f) * (bc.w - bc.y + 1.0f);
                for (int k = 0; k < nkeep; ++k) {
                    float xx1 = fmaxf(skx1[k], bc.x);
                    float yy1 = fmaxf(sky1[k], bc.y);
                    float xx2 = fminf(skx2[k], bc.z);
                    float yy2 = fminf(sky2[k], bc.w);
                    float iw = fmaxf(0.0f, xx2 - xx1 + 1.0f);
                    float ih = fmaxf(0.0f, yy2 - yy1 + 1.0f);
                    float inter = iw * ih;
                    float iou = inter / ((skar[k] + ac) - inter);
                    if (iou > NMS_THRESH) sup = true;
                }
                uint64_t live = __ballot(!sup);
                while (live != 0ull && nkeep < POST_NMS) {
                    int j = (int)__builtin_ctzll(live);
                    int cj = base + j;
                    if (l == 0) keepL[nkeep] = cj;
                    float jx1 = __shfl(bc.x, j);
                    float jy1 = __shfl(bc.y, j);
                    float jx2 = __shfl(bc.z, j);
                    float jy2 = __shfl(bc.w, j);
                    float ja  = __shfl(ac, j);
                    if (l == 0) { skx1[nkeep]=jx1; sky1[nkeep]=jy1; skx2[nkeep]=jx2; sky2[nkeep]=jy2; skar[nkeep]=ja; }
                    nkeep++;
                    float xx1 = fmaxf(jx1, bc.x);
                    float yy1 = fmaxf(jy1, bc.y);
                    float xx2 = fminf(jx2, bc.z);
                    float yy2 = fminf(jy2, bc.w);
                    float iw = fmaxf(0.0f, xx2 - xx1 + 1.0f);
                    float ih = fmaxf(0.0f, yy2 - yy1 + 1.0f);
                    float inter = iw * ih;
                    float iou = inter / ((ja + ac) - inter);
                    uint64_t kill = __ballot(iou > NMS_THRESH);
                    live &= ~kill;
                    live &= ~(1ull << j);
                }
                base += 64;
            }
        }

        // ---- output (same wave: LDS program order guarantees visibility) ----
        for (int k = l; k < POST_NMS; k += 64) {
            float* o = out + ((size_t)b*POST_NMS + k)*5;
            o[0] = (float)b;
            if (k < nkeep) {
                float4 bx = *(const float4*)(topb + ((size_t)b*PRE_NMS + keepL[k])*4);
                o[1] = bx.x; o[2] = bx.y; o[3] = bx.z; o[4] = bx.w;
            } else {
                o[1] = 0.0f; o[2] = 0.0f; o[3] = 0.0f; o[4] = 0.0f;
            }
        }
    }
}

extern "C" void kernel_launch(void* const* d_in, const int* in_sizes, int n_in,
                              void* d_out, int out_size, void* d_ws, size_t ws_size,
                              hipStream_t stream) {
    const float* scores   = (const float*)d_in[0];
    const float* deltas   = (const float*)d_in[1];
    const float* img_info = (const float*)d_in[2];
    const float* anchors  = (const float*)d_in[3];
    float* out = (float*)d_out;

    uint8_t* ws = (uint8_t*)d_ws;
    float*    topb  = (float*)(ws + OFF_TOPB);
    uint64_t* msk   = (uint64_t*)(ws + OFF_MSK);
    uint32_t* Hg    = (uint32_t*)(ws + OFF_H);
    uint32_t* SSg   = (uint32_t*)(ws + OFF_SS);
    uint32_t* CURg  = (uint32_t*)(ws + OFF_CUR);
    uint32_t* B1g   = (uint32_t*)(ws + OFF_B1);
    uint32_t* NselG = (uint32_t*)(ws + OFF_NSEL);
    uint64_t* scatG = (uint64_t*)(ws + OFF_SCAT);

    hipMemsetAsync(Hg, 0, (size_t)NB*BINS*4, stream);

    hist_kernel<<<(NB*N_PER)/1024, 1024, 0, stream>>>(scores, Hg);
    scan_cutoff<<<NB, 1024, 0, stream>>>(Hg, SSg, CURg, B1g, NselG);
    scatter_kernel<<<(NB*N_PER)/1024, 1024, 0, stream>>>(scores, B1g, CURg, scatG);
    rank_decode<<<dim3(SCAT_MAX/1000, NB), 1024, 0, stream>>>(scatG, SSg, CURg, NselG,
                                                              deltas, img_info, anchors, topb);

    dim3 mg(MW, MW, NB);
    nms_mask_small<<<mg, 64, 0, stream>>>(topb, msk);

    nms_scan_lds<<<NB, 256, 0, stream>>>(msk, topb, out);
}

// Round 14
// 170.832 us; speedup vs baseline: 1.1204x; 1.1204x over previous
//
#include <hip/hip_runtime.h>
#include <stdint.h>

#define HH 64
#define WW 64
#define AA 9
#define N_PER (HH*WW*AA)   // 36864
#define NB 4
#define PRE_NMS 6000
#define POST_NMS 300
#define NMS_THRESH 0.7f
#define FEAT_STRIDE 16
#define M 1024             // in-LDS NMS candidate window
#define MW 16              // u64 words per mask row (1024/64)
#define BINS 65536         // 16-bit radix bins (top bits of monotonic key)
#define KSHIFT 48
#define SCAT_MAX 8000      // scatter capacity (Nsel < 6000 + maxbin ~80)

// ws layout (bytes)
#define OFF_TOPB   0u          // 384,000
#define OFF_MSK    393216u     // 524,288
#define OFF_H      917504u     // 1,048,576
#define OFF_SS     1966080u    // 1,048,576
#define OFF_CUR    3014656u    // 1,048,576
#define OFF_B1     4063232u    // 16
#define OFF_NSEL   4063248u    // 16
#define OFF_SCAT   4063264u    // 256,000

__device__ __forceinline__ uint64_t make_key(const float* __restrict__ scores, int b, int j) {
    int a = j >> 12, hw = j & 4095;
    float sc = scores[((size_t)b*18 + 9 + a)*4096 + hw];
    uint32_t u = __float_as_uint(sc);
    u = (u & 0x80000000u) ? ~u : (u | 0x80000000u);   // monotonic float->uint
    uint32_t i = (uint32_t)(hw*9 + a);                // reference flat index
    return ((uint64_t)u << 32) | (uint32_t)(~i);
}

// ---------------- K1: grid-parallel 16-bit histogram ----------------
__global__ void __launch_bounds__(1024) hist_kernel(const float* __restrict__ scores,
                                                    uint32_t* __restrict__ Hg) {
    int tid = blockIdx.x*1024 + threadIdx.x;          // 0..147455
    int b = tid / N_PER;
    int j = tid - b*N_PER;
    uint64_t k64 = make_key(scores, b, j);
    atomicAdd(&Hg[(uint32_t)b*BINS + (uint32_t)(k64 >> KSHIFT)], 1u);
}

// ---------------- K2: per-image suffix scan + cutoff (65536 bins) ----------------
// Barrier-light: wave-level shfl suffix scan (no barriers) + 16 wave-sums
// scanned by wave 0 -> 3 __syncthreads total (was ~20 with Hillis-Steele).
__global__ void __launch_bounds__(1024) scan_cutoff(const uint32_t* __restrict__ Hg,
                                                    uint32_t* __restrict__ SSg,
                                                    uint32_t* __restrict__ CURg,
                                                    uint32_t* __restrict__ B1g,
                                                    uint32_t* __restrict__ NselG) {
    int b = blockIdx.x;
    int t = threadIdx.x;
    int wid = t >> 6, lane = t & 63;
    __shared__ uint32_t wsum[16];
    __shared__ uint32_t wsuf[16];
    __shared__ int shB1;
    __shared__ uint32_t shNsel;

    uint32_t base = (uint32_t)t * 64u;
    const uint32_t* Hb = Hg + (size_t)b*BINS;
    uint32_t loc[64];
    uint32_t lsum = 0;
    #pragma unroll
    for (int k = 0; k < 16; ++k) {
        uint4 v = ((const uint4*)(Hb + base))[k];
        loc[4*k+0] = v.x; loc[4*k+1] = v.y; loc[4*k+2] = v.z; loc[4*k+3] = v.w;
        lsum += v.x + v.y + v.z + v.w;
    }
    // wave-level inclusive SUFFIX scan of lsum (lane l gets sum over lanes >= l)
    uint32_t v = lsum;
    #pragma unroll
    for (int off = 1; off < 64; off <<= 1) {
        uint32_t u = __shfl_down(v, off);
        if (lane + off < 64) v += u;
    }
    if (lane == 0) wsum[wid] = v;                     // per-wave total
    __syncthreads();
    if (wid == 0 && lane < 16) {                      // suffix scan of 16 wave sums
        uint32_t s = wsum[lane];
        #pragma unroll
        for (int off = 1; off < 16; off <<= 1) {
            uint32_t u = __shfl_down(s, off);
            if (lane + off < 16) s += u;
        }
        wsuf[lane] = s;                               // inclusive suffix over waves
    }
    __syncthreads();
    uint32_t incl = v + ((wid + 1 < 16) ? wsuf[wid + 1] : 0u);  // inclusive suffix at thread t
    // in-place: loc[k] := SS[base+k] (exclusive suffix); run starts at incl - lsum
    uint32_t run = incl - lsum;
    #pragma unroll
    for (int k = 63; k >= 0; --k) { uint32_t h = loc[k]; loc[k] = run; run += h; }
    // find B1: SS[i] < 6000 <= SS[i-1]  (SS[base-1] == incl)
    #pragma unroll
    for (int k = 0; k < 64; ++k) {
        uint32_t ss   = loc[k];
        uint32_t prev = (k == 0) ? incl : loc[k-1];
        if (ss < PRE_NMS && prev >= PRE_NMS) { shB1 = (int)(base + (uint32_t)k); shNsel = prev; }
    }
    __syncthreads();
    int B1 = shB1;
    if (t == 0) { B1g[b] = (uint32_t)B1; NselG[b] = shNsel; }
    // write SS and CUR (cursor init = SS) only for bins >= B1
    uint32_t* SSb  = SSg  + (size_t)b*BINS;
    uint32_t* CURb = CURg + (size_t)b*BINS;
    if ((int)base >= B1) {                            // fully above: vector path
        #pragma unroll
        for (int k = 0; k < 16; ++k) {
            uint4 w = make_uint4(loc[4*k+0], loc[4*k+1], loc[4*k+2], loc[4*k+3]);
            ((uint4*)(SSb + base))[k]  = w;
            ((uint4*)(CURb + base))[k] = w;
        }
    } else if ((int)(base + 63u) >= B1) {             // straddling thread: scalar tail
        #pragma unroll
        for (int k = 0; k < 64; ++k) {
            if ((int)(base + (uint32_t)k) >= B1) {
                SSb[base + k]  = loc[k];
                CURb[base + k] = loc[k];
            }
        }
    }
}

// ---------------- K3: grid-parallel scatter (bin-partitioned slots) ----------------
__global__ void __launch_bounds__(1024) scatter_kernel(const float* __restrict__ scores,
                                                       const uint32_t* __restrict__ B1g,
                                                       uint32_t* __restrict__ CURg,
                                                       uint64_t* __restrict__ scatG) {
    int tid = blockIdx.x*1024 + threadIdx.x;
    int b = tid / N_PER;
    int j = tid - b*N_PER;
    uint64_t k64 = make_key(scores, b, j);
    uint32_t bin = (uint32_t)(k64 >> KSHIFT);
    if (bin >= B1g[b]) {
        uint32_t slot = atomicAdd(&CURg[(uint32_t)b*BINS + bin], 1u);
        if (slot < SCAT_MAX) scatG[(uint32_t)b*SCAT_MAX + slot] = k64;
    }
}

// ---------------- K4: grid-parallel rank + decode + direct topb[rank] ----------------
__global__ void __launch_bounds__(1024) rank_decode(const uint64_t* __restrict__ scatG,
                                                    const uint32_t* __restrict__ SSg,
                                                    const uint32_t* __restrict__ CURg,
                                                    const uint32_t* __restrict__ NselG,
                                                    const float* __restrict__ deltas,
                                                    const float* __restrict__ img_info,
                                                    const float* __restrict__ anchors,
                                                    float* __restrict__ topb) {
#pragma clang fp contract(off)
    int b = blockIdx.y;
    uint32_t s = blockIdx.x*1024u + threadIdx.x;
    uint32_t n = min(NselG[b], (uint32_t)SCAT_MAX);
    if (s >= n) return;
    const uint64_t* sg = scatG + (uint32_t)b*SCAT_MAX;
    uint64_t k64 = sg[s];
    uint32_t bin = (uint32_t)(k64 >> KSHIFT);
    uint32_t start = SSg[(uint32_t)b*BINS + bin];
    uint32_t end = min(CURg[(uint32_t)b*BINS + bin], (uint32_t)SCAT_MAX);
    uint32_t cnt = 0;
    uint32_t j = start;
    for (; j + 4 <= end; j += 4) {
        uint64_t a0 = sg[j], a1 = sg[j+1], a2 = sg[j+2], a3 = sg[j+3];
        cnt += (a0 > k64) ? 1u : 0u;
        cnt += (a1 > k64) ? 1u : 0u;
        cnt += (a2 > k64) ? 1u : 0u;
        cnt += (a3 > k64) ? 1u : 0u;
    }
    for (; j < end; ++j) cnt += (sg[j] > k64) ? 1u : 0u;
    uint32_t r = start + cnt;                         // exact global descending rank
    if (r >= PRE_NMS) return;

    uint32_t i = ~(uint32_t)(k64 & 0xFFFFFFFFu);
    int a = (int)(i % 9u);
    int hw = (int)(i / 9u);
    int h = hw >> 6, w = hw & 63;
    float sx = (float)(w * FEAT_STRIDE);
    float sy = (float)(h * FEAT_STRIDE);
    float ax1 = anchors[a*4+0] + sx;
    float ay1 = anchors[a*4+1] + sy;
    float ax2 = anchors[a*4+2] + sx;
    float ay2 = anchors[a*4+3] + sy;
    float width  = ax2 - ax1 + 1.0f;
    float height = ay2 - ay1 + 1.0f;
    float cx = ax1 + 0.5f * width;
    float cy = ay1 + 0.5f * height;
    size_t dbase = ((size_t)b*36 + a*4) * 4096 + hw;
    float dx = deltas[dbase];
    float dy = deltas[dbase + 4096];
    float dw = deltas[dbase + 2*4096];
    float dh = deltas[dbase + 3*4096];
    float pcx = dx * width + cx;
    float pcy = dy * height + cy;
    float pw = (float)exp((double)dw) * width;        // correctly-rounded f32 exp
    float ph = (float)exp((double)dh) * height;
    float x1 = pcx - 0.5f * pw;
    float y1 = pcy - 0.5f * ph;
    float x2 = pcx + 0.5f * pw;
    float y2 = pcy + 0.5f * ph;
    float maxx = img_info[1] - 1.0f;
    float maxy = img_info[0] - 1.0f;
    x1 = fminf(fmaxf(x1, 0.0f), maxx);
    y1 = fminf(fmaxf(y1, 0.0f), maxy);
    x2 = fminf(fmaxf(x2, 0.0f), maxx);
    y2 = fminf(fmaxf(y2, 0.0f), maxy);
    *(float4*)(topb + ((size_t)b*PRE_NMS + r)*4) = make_float4(x1, y1, x2, y2);
}

// =====================================================================
// Kernel 5: suppression bitmask for the TOP-1024 window (unchanged).
// =====================================================================
__global__ void __launch_bounds__(64) nms_mask_small(const float* __restrict__ topb,
                                                     uint64_t* __restrict__ msk) {
#pragma clang fp contract(off)
    int jblock = blockIdx.x;  // 0..15
    int iblock = blockIdx.y;  // 0..15
    int b = blockIdx.z;
    int t = threadIdx.x;      // 0..63
    __shared__ float4 jb[64];
    __shared__ float jarea[64];
    int j0 = jblock*64;
    {
        float4 bj = *(const float4*)(topb + ((size_t)b*PRE_NMS + j0 + t)*4);
        jb[t] = bj;
        jarea[t] = (bj.z - bj.x + 1.0f) * (bj.w - bj.y + 1.0f);
    }
    __syncthreads();
    int i = iblock*64 + t;
    float4 bi = *(const float4*)(topb + ((size_t)b*PRE_NMS + i)*4);
    float areai = (bi.z - bi.x + 1.0f) * (bi.w - bi.y + 1.0f);
    uint64_t bits = 0;
    for (int jj = 0; jj < 64; ++jj) {
        float4 bj = jb[jj];
        float xx1 = fmaxf(bi.x, bj.x);
        float yy1 = fmaxf(bi.y, bj.y);
        float xx2 = fminf(bi.z, bj.z);
        float yy2 = fminf(bi.w, bj.w);
        float iw = fmaxf(0.0f, xx2 - xx1 + 1.0f);
        float ih = fmaxf(0.0f, yy2 - yy1 + 1.0f);
        float inter = iw * ih;
        float iou = inter / ((areai + jarea[jj]) - inter);
        if (iou > NMS_THRESH) bits |= (1ull << jj);
    }
    msk[((size_t)b*M + i)*MW + jblock] = bits;
}

// =====================================================================
// Kernel 6: single-wave greedy scan, mask fully in LDS.
// Reverted to the round-12 structure (measured 44.8 us): simple exact
// walk, no speculation (1-deep prefetch consumed next-iteration-start
// hides nothing and the 2nd ballot/readlane chain cost +20 us).
// =====================================================================
__global__ void __launch_bounds__(64) nms_scan_lds(const uint64_t* __restrict__ msk,
                                                   const float* __restrict__ topb,
                                                   float* __restrict__ out) {
#pragma clang fp contract(off)
    int b = blockIdx.x;
    int l = threadIdx.x;
    __shared__ __align__(16) uint64_t rows[M][MW];   // 131,072 B
    __shared__ int keepL[POST_NMS];
    __shared__ float skx1[POST_NMS], sky1[POST_NMS], skx2[POST_NMS], sky2[POST_NMS], skar[POST_NMS];

    const uint8_t* src0 = (const uint8_t*)(msk + (size_t)b*M*MW);
    uint8_t* dst0 = (uint8_t*)&rows[0][0];
    for (int it = 0; it < (M*MW*8)/1024; ++it) {     // 128 issues of 1 KB
        __builtin_amdgcn_global_load_lds(
            (const __attribute__((address_space(1))) uint32_t*)(src0 + it*1024 + l*16),
            (__attribute__((address_space(3))) uint32_t*)(dst0 + it*1024 + l*16),
            16, 0, 0);
    }
    asm volatile("s_waitcnt vmcnt(0)" ::: "memory");
    __builtin_amdgcn_sched_barrier(0);

    uint64_t remv = 0ull;      // lane l<16 owns bits [64l, 64l+64)
    int nkeep = 0;
    int cur = 0;
    bool exhausted = false;
    while (true) {
        if (l == 0) keepL[nkeep] = cur;
        nkeep++;
        if (nkeep >= POST_NMS) break;
        uint64_t rw = (l < MW) ? rows[cur][l] : 0ull;
        remv |= rw;            // row includes self-bit (IoU=1)
        uint64_t live = (l < MW) ? ~remv : 0ull;
        int local = live ? (l*64 + (int)__builtin_ctzll(live)) : 0x7FFFFFFF;
        uint64_t mb = __ballot(live != 0ull);
        if (mb == 0ull) { exhausted = true; break; }
        cur = __builtin_amdgcn_readlane(local, (int)__builtin_ctzll(mb));
    }

    if (nkeep < POST_NMS && exhausted) {
        for (int k = l; k < nkeep; k += 64) {
            float4 bx = *(const float4*)(topb + ((size_t)b*PRE_NMS + keepL[k])*4);
            skx1[k] = bx.x; sky1[k] = bx.y; skx2[k] = bx.z; sky2[k] = bx.w;
            skar[k] = (bx.z - bx.x + 1.0f) * (bx.w - bx.y + 1.0f);
        }
        int base = M;
        while (nkeep < POST_NMS && base < PRE_NMS) {
            int c = base + l;
            float4 bc = make_float4(0.f, 0.f, 0.f, 0.f);
            bool sup = true;
            if (c < PRE_NMS) {
                bc = *(const float4*)(topb + ((size_t)b*PRE_NMS + c)*4);
                sup = false;
            }
            float ac = (bc.z - bc.x + 1.0f) * (bc.w - bc.y + 1.0f);
            for (int k = 0; k < nkeep; ++k) {
                float xx1 = fmaxf(skx1[k], bc.x);
                float yy1 = fmaxf(sky1[k], bc.y);
                float xx2 = fminf(skx2[k], bc.z);
                float yy2 = fminf(sky2[k], bc.w);
                float iw = fmaxf(0.0f, xx2 - xx1 + 1.0f);
                float ih = fmaxf(0.0f, yy2 - yy1 + 1.0f);
                float inter = iw * ih;
                float iou = inter / ((skar[k] + ac) - inter);
                if (iou > NMS_THRESH) sup = true;
            }
            uint64_t live = __ballot(!sup);
            while (live != 0ull && nkeep < POST_NMS) {
                int j = (int)__builtin_ctzll(live);
                int cj = base + j;
                if (l == 0) keepL[nkeep] = cj;
                float jx1 = __shfl(bc.x, j);
                float jy1 = __shfl(bc.y, j);
                float jx2 = __shfl(bc.z, j);
                float jy2 = __shfl(bc.w, j);
                float ja  = __shfl(ac, j);
                if (l == 0) { skx1[nkeep]=jx1; sky1[nkeep]=jy1; skx2[nkeep]=jx2; sky2[nkeep]=jy2; skar[nkeep]=ja; }
                nkeep++;
                float xx1 = fmaxf(jx1, bc.x);
                float yy1 = fmaxf(jy1, bc.y);
                float xx2 = fminf(jx2, bc.z);
                float yy2 = fminf(jy2, bc.w);
                float iw = fmaxf(0.0f, xx2 - xx1 + 1.0f);
                float ih = fmaxf(0.0f, yy2 - yy1 + 1.0f);
                float inter = iw * ih;
                float iou = inter / ((ja + ac) - inter);
                uint64_t kill = __ballot(iou > NMS_THRESH);
                live &= ~kill;
                live &= ~(1ull << j);
            }
            base += 64;
        }
    }
    __syncthreads();

    for (int k = l; k < POST_NMS; k += 64) {
        float* o = out + ((size_t)b*POST_NMS + k)*5;
        o[0] = (float)b;
        if (k < nkeep) {
            float4 bx = *(const float4*)(topb + ((size_t)b*PRE_NMS + keepL[k])*4);
            o[1] = bx.x; o[2] = bx.y; o[3] = bx.z; o[4] = bx.w;
        } else {
            o[1] = 0.0f; o[2] = 0.0f; o[3] = 0.0f; o[4] = 0.0f;
        }
    }
}

extern "C" void kernel_launch(void* const* d_in, const int* in_sizes, int n_in,
                              void* d_out, int out_size, void* d_ws, size_t ws_size,
                              hipStream_t stream) {
    const float* scores   = (const float*)d_in[0];
    const float* deltas   = (const float*)d_in[1];
    const float* img_info = (const float*)d_in[2];
    const float* anchors  = (const float*)d_in[3];
    float* out = (float*)d_out;

    uint8_t* ws = (uint8_t*)d_ws;
    float*    topb  = (float*)(ws + OFF_TOPB);
    uint64_t* msk   = (uint64_t*)(ws + OFF_MSK);
    uint32_t* Hg    = (uint32_t*)(ws + OFF_H);
    uint32_t* SSg   = (uint32_t*)(ws + OFF_SS);
    uint32_t* CURg  = (uint32_t*)(ws + OFF_CUR);
    uint32_t* B1g   = (uint32_t*)(ws + OFF_B1);
    uint32_t* NselG = (uint32_t*)(ws + OFF_NSEL);
    uint64_t* scatG = (uint64_t*)(ws + OFF_SCAT);

    hipMemsetAsync(Hg, 0, (size_t)NB*BINS*4, stream);

    hist_kernel<<<(NB*N_PER)/1024, 1024, 0, stream>>>(scores, Hg);
    scan_cutoff<<<NB, 1024, 0, stream>>>(Hg, SSg, CURg, B1g, NselG);
    scatter_kernel<<<(NB*N_PER)/1024, 1024, 0, stream>>>(scores, B1g, CURg, scatG);
    rank_decode<<<dim3(SCAT_MAX/1000, NB), 1024, 0, stream>>>(scatG, SSg, CURg, NselG,
                                                              deltas, img_info, anchors, topb);

    dim3 mg(MW, MW, NB);
    nms_mask_small<<<mg, 64, 0, stream>>>(topb, msk);

    nms_scan_lds<<<NB, 64, 0, stream>>>(msk, topb, out);
}